// Round 7
// baseline (784.202 us; speedup 1.0000x reference)
//
#include <hip/hip_runtime.h>
#include <hip/hip_fp16.h>
#include <hip/hip_cooperative_groups.h>

namespace cg = cooperative_groups;

#define N_NODES 50000
#define N_EDGES 500000
#define DIM 64
#define KDIM 4
#define HID 64
#define NCLS 40
#define NBLK ((N_NODES + 255) / 256)   // 196
#define ZN (50176 + 512)               // cnt(padded) + bflag(256) + bval(256)

__device__ inline unsigned pack2(float a, float b) {
    __half2 h = __floats2half2_rn(a, b);
    return *(unsigned*)&h;
}
__device__ inline float2 unpack2(unsigned u) {
    __half2 h = *(__half2*)&u;
    return __half22float2(h);
}

// ---- edge load/compute split for the per-edge MLP (fp16 y) ----
__device__ inline void load_edge(const uint4 r, const unsigned* __restrict__ y,
                                 int lane, uint2& q0, uint2& q1, uint2& q2, uint2& q3) {
    int sn = (int)r.x;
    const uint2* yb = (const uint2*)(y + (size_t)sn * 128);
    q0 = yb[lane];
    q1 = yb[16 + lane];
    q2 = yb[32 + lane];
    q3 = yb[48 + lane];
}

__device__ inline void compute_edge(const uint4 r, uint2 q0, uint2 q1, uint2 q2, uint2 q3,
                                    const float4 bias, float4& acc) {
    float2 e01 = unpack2(r.y);
    float2 e23 = unpack2(r.z);
    float2 a0 = unpack2(q0.x), a1 = unpack2(q0.y);
    float2 b0 = unpack2(q1.x), b1 = unpack2(q1.y);
    float2 c0 = unpack2(q2.x), c1 = unpack2(q2.y);
    float2 d0 = unpack2(q3.x), d1 = unpack2(q3.y);

    float4 z = bias;
    z.x = fmaf(e01.x, a0.x, z.x); z.y = fmaf(e01.x, a0.y, z.y);
    z.z = fmaf(e01.x, a1.x, z.z); z.w = fmaf(e01.x, a1.y, z.w);
    z.x = fmaf(e01.y, b0.x, z.x); z.y = fmaf(e01.y, b0.y, z.y);
    z.z = fmaf(e01.y, b1.x, z.z); z.w = fmaf(e01.y, b1.y, z.w);
    z.x = fmaf(e23.x, c0.x, z.x); z.y = fmaf(e23.x, c0.y, z.y);
    z.z = fmaf(e23.x, c1.x, z.z); z.w = fmaf(e23.x, c1.y, z.w);
    z.x = fmaf(e23.y, d0.x, z.x); z.y = fmaf(e23.y, d0.y, z.y);
    z.z = fmaf(e23.y, d1.x, z.z); z.w = fmaf(e23.y, d1.y, z.w);

    acc.x += fmaxf(z.x, 0.f);
    acc.y += fmaxf(z.y, 0.f);
    acc.z += fmaxf(z.z, 0.f);
    acc.w += fmaxf(z.w, 0.f);
}

// ---- aggregate core: unroll-4, batched loads; rec2 strided by 2 uint4 ----
__device__ inline float4 agg_core(const uint4* __restrict__ rec2,
                                  const int* __restrict__ start,
                                  const int* __restrict__ cnt,
                                  const unsigned* __restrict__ y,
                                  const float* __restrict__ b,
                                  int g, int lane) {
    int s0 = start[g];
    int deg = cnt[g];
    int s1 = s0 + deg;

    float4 bias = ((const float4*)b)[lane];
    float4 acc = make_float4(0.f, 0.f, 0.f, 0.f);

    int i = s0;
    for (; i + 4 <= s1; i += 4) {
        uint4 r0 = rec2[2 * i + 0];
        uint4 r1 = rec2[2 * i + 2];
        uint4 r2 = rec2[2 * i + 4];
        uint4 r3 = rec2[2 * i + 6];
        uint2 a0, a1, a2, a3, b0, b1, b2, b3, c0, c1, c2, c3, d0, d1, d2, d3;
        load_edge(r0, y, lane, a0, a1, a2, a3);
        load_edge(r1, y, lane, b0, b1, b2, b3);
        load_edge(r2, y, lane, c0, c1, c2, c3);
        load_edge(r3, y, lane, d0, d1, d2, d3);
        compute_edge(r0, a0, a1, a2, a3, bias, acc);
        compute_edge(r1, b0, b1, b2, b3, bias, acc);
        compute_edge(r2, c0, c1, c2, c3, bias, acc);
        compute_edge(r3, d0, d1, d2, d3, bias, acc);
    }
    if (i + 2 <= s1) {
        uint4 r0 = rec2[2 * i + 0];
        uint4 r1 = rec2[2 * i + 2];
        uint2 a0, a1, a2, a3, b0, b1, b2, b3;
        load_edge(r0, y, lane, a0, a1, a2, a3);
        load_edge(r1, y, lane, b0, b1, b2, b3);
        compute_edge(r0, a0, a1, a2, a3, bias, acc);
        compute_edge(r1, b0, b1, b2, b3, bias, acc);
        i += 2;
    }
    if (i < s1) {
        uint4 r0 = rec2[2 * i];
        uint2 a0, a1, a2, a3;
        load_edge(r0, y, lane, a0, a1, a2, a3);
        compute_edge(r0, a0, a1, a2, a3, bias, acc);
    }

    float inv = 1.0f / (float)(deg > 1 ? deg : 1);
    float4 r;
    r.x = fmaxf(acc.x * inv, 0.f);
    r.y = fmaxf(acc.y * inv, 0.f);
    r.z = fmaxf(acc.z * inv, 0.f);
    r.w = fmaxf(acc.w * inv, 0.f);
    return r;
}

// ---- transform phase: y[n, k*64+h] = sum_d hin[n,d]*W[(k*64+d)*64+h], fp16 out ----
// tiles = 782 node-tiles x 4 k-slices, grid-stride. LDS: sW 16KB + sh 16.6KB.
__device__ inline void transform_phase(const float* __restrict__ hin,
                                       const float* __restrict__ W,
                                       unsigned* __restrict__ y,
                                       float* smem, int t, int b, int gsz) {
    float* sW = smem;            // 4096 floats
    float* sh = smem + 4096;     // 64*65 floats
    const int NT = (N_NODES + 63) / 64;   // 782
    for (int tile = b; tile < NT * 4; tile += gsz) {
        int nt = tile >> 2;
        int ks = tile & 3;
        __syncthreads();   // protect previous iteration's LDS reads
        // stage W k-slice: 4096 floats = 1024 float4 -> 4 per thread
        const float4* W4 = (const float4*)(W + (size_t)ks * 4096);
        float4* sW4 = (float4*)sW;
#pragma unroll
        for (int i = 0; i < 4; ++i) sW4[t + 256 * i] = W4[t + 256 * i];
        // stage h tile: 64 nodes x 16 float4
        int n0 = nt * 64;
#pragma unroll
        for (int i = 0; i < 4; ++i) {
            int idx = t + 256 * i;
            int nl = idx >> 4;
            int dg = idx & 15;
            int n = n0 + nl;
            float4 v = make_float4(0.f, 0.f, 0.f, 0.f);
            if (n < N_NODES) v = ((const float4*)hin)[(size_t)n * 16 + dg];
            sh[nl * 65 + dg * 4 + 0] = v.x;
            sh[nl * 65 + dg * 4 + 1] = v.y;
            sh[nl * 65 + dg * 4 + 2] = v.z;
            sh[nl * 65 + dg * 4 + 3] = v.w;
        }
        __syncthreads();

        int nl = t >> 2;          // 0..63
        int cg = t & 3;           // 0..3
        int hc0 = cg * 16;

        float acc[16];
#pragma unroll
        for (int j = 0; j < 16; ++j) acc[j] = 0.f;

        for (int d = 0; d < 64; ++d) {
            float a0 = sh[nl * 65 + d];
            const float* wr = &sW[d * 64 + hc0];
#pragma unroll
            for (int j = 0; j < 16; ++j) acc[j] = fmaf(a0, wr[j], acc[j]);
        }

        int n = n0 + nl;
        if (n < N_NODES) {
            uint4* o = (uint4*)(y + (size_t)n * 128 + ks * 32 + cg * 8);
            o[0] = make_uint4(pack2(acc[0], acc[1]), pack2(acc[2], acc[3]),
                              pack2(acc[4], acc[5]), pack2(acc[6], acc[7]));
            o[1] = make_uint4(pack2(acc[8], acc[9]), pack2(acc[10], acc[11]),
                              pack2(acc[12], acc[13]), pack2(acc[14], acc[15]));
        }
    }
}

// ---- THE fused kernel: all phases, one launch ----
__global__ __launch_bounds__(256, 4) void fused_k(
    const float* __restrict__ nf, const float* __restrict__ ef,
    const int* __restrict__ src, const int* __restrict__ dst,
    const float* __restrict__ W0, const float* __restrict__ b0,
    const float* __restrict__ W1, const float* __restrict__ b1,
    const float* __restrict__ Wfc, const float* __restrict__ bfc,
    float* __restrict__ out,
    int* cnt, int* bflag, int* bval, int* start, int* cursor,
    uint4* rec, unsigned* y, float* hbuf) {
    cg::grid_group grid = cg::this_grid();
    __shared__ float smem[8256];   // 33 KB union
    int t = threadIdx.x;
    int b = blockIdx.x;
    int gsz = gridDim.x;
    int gtid = b * 256 + t;
    int gthreads = gsz * 256;

    // P0: zero cnt + bflag + bval (contiguous allocation)
    for (int i = gtid; i < ZN; i += gthreads) cnt[i] = 0;
    grid.sync();

    // P1: in-degree histogram
    for (int e = gtid; e < N_EDGES; e += gthreads) atomicAdd(&cnt[dst[e]], 1);
    grid.sync();

    // P2: exclusive scan, blocks 0..NBLK-1, decoupled lookback (all blocks resident)
    if (b < NBLK) {
        int* ls = (int*)smem;          // [0..255] scan, [256] ok_all, [257] sbase
        int n = b * 256 + t;
        int v = (n < N_NODES) ? cnt[n] : 0;
        ls[t] = v;
        __syncthreads();
#pragma unroll
        for (int off = 1; off < 256; off <<= 1) {
            int u = (t >= off) ? ls[t - off] : 0;
            __syncthreads();
            ls[t] += u;
            __syncthreads();
        }
        int incl = ls[t];
        int total = ls[255];
        __syncthreads();

        if (t == 0) {
            bval[b] = total;
            __threadfence();
            bflag[b] = 1;
        }

        if (b > 0) {
            volatile int* vf = (volatile int*)bflag;
            for (;;) {
                int f = (t < b) ? vf[t] : 1;
                if (t == 0) ls[256] = 1;
                __syncthreads();
                if (!f) ls[256] = 0;
                __syncthreads();
                if (ls[256]) break;
            }
            __threadfence();
            int pv = (t < b) ? bval[t] : 0;
            ls[t] = pv;
            __syncthreads();
#pragma unroll
            for (int off = 128; off > 0; off >>= 1) {
                if (t < off) ls[t] += ls[t + off];
                __syncthreads();
            }
            if (t == 0) ls[257] = ls[0];
            __syncthreads();
        } else {
            if (t == 0) ls[257] = 0;
            __syncthreads();
        }

        int excl = ls[257] + incl - v;
        if (n < N_NODES) { start[n] = excl; cursor[n] = excl; }
        if (n == 0) start[N_NODES] = N_EDGES;
    }
    grid.sync();

    // P3: counting-sort scatter, interleaved 32B records per edge
    for (int e = gtid; e < N_EDGES; e += gthreads) {
        int d = dst[e];
        int pos = atomicAdd(&cursor[d], 1);
        int sn = src[e];
        float4 f0 = ((const float4*)ef)[e];
        float4 f1 = ((const float4*)ef)[N_EDGES + e];
        rec[2 * pos]     = make_uint4((unsigned)sn, pack2(f0.x, f0.y), pack2(f0.z, f0.w), 0u);
        rec[2 * pos + 1] = make_uint4((unsigned)sn, pack2(f1.x, f1.y), pack2(f1.z, f1.w), 0u);
    }
    grid.sync();

    // P4: transform layer 0
    transform_phase(nf, W0, y, smem, t, b, gsz);
    grid.sync();

    // P5: aggregate layer 0 -> hbuf
    {
        int nl = t >> 4;
        int lane = t & 15;
        for (int nb = b; nb < N_NODES / 16; nb += gsz) {
            int g = nb * 16 + nl;
            float4 r = agg_core(rec, start, cnt, y, b0, g, lane);
            ((float4*)hbuf)[(size_t)g * 16 + lane] = r;
        }
    }
    grid.sync();

    // P6: transform layer 1
    transform_phase(hbuf, W1, y, smem, t, b, gsz);
    grid.sync();

    // P7: aggregate layer 1 + fused classifier
    {
        float* sh_h  = smem;                       // 16*65
        float* sWfcT = smem + 16 * 65;             // 40*65, transposed+padded
        float* sbfc  = smem + 16 * 65 + NCLS * 65; // 40
        for (int i = t; i < 64 * NCLS; i += 256) {
            int j = i / NCLS;
            int c = i - j * NCLS;
            sWfcT[c * 65 + j] = Wfc[i];
        }
        if (t < NCLS) sbfc[t] = bfc[t];
        __syncthreads();

        int nl = t >> 4;
        int lane = t & 15;
        for (int nb = b; nb < N_NODES / 16; nb += gsz) {
            int g = nb * 16 + nl;
            float4 r = agg_core(rec + 1, start, cnt, y, b1, g, lane);
            sh_h[nl * 65 + lane * 4 + 0] = r.x;
            sh_h[nl * 65 + lane * 4 + 1] = r.y;
            sh_h[nl * 65 + lane * 4 + 2] = r.z;
            sh_h[nl * 65 + lane * 4 + 3] = r.w;
            __syncthreads();
            for (int item = t; item < 16 * NCLS; item += 256) {
                int rn = item / NCLS;
                int c = item - rn * NCLS;
                float acc = sbfc[c];
                const float* hr = &sh_h[rn * 65];
                const float* wc = &sWfcT[c * 65];
#pragma unroll
                for (int j = 0; j < 64; ++j) acc = fmaf(hr[j], wc[j], acc);
                out[(size_t)(nb * 16 + rn) * NCLS + c] = acc;
            }
            __syncthreads();
        }
    }
}

extern "C" void kernel_launch(void* const* d_in, const int* in_sizes, int n_in,
                              void* d_out, int out_size, void* d_ws, size_t ws_size,
                              hipStream_t stream) {
    const float* nf  = (const float*)d_in[0];
    const float* ef  = (const float*)d_in[1];
    const int*   src = (const int*)d_in[2];
    const int*   dst = (const int*)d_in[3];
    const float* W0  = (const float*)d_in[4];
    const float* b0  = (const float*)d_in[5];
    const float* W1  = (const float*)d_in[6];
    const float* b1  = (const float*)d_in[7];
    const float* Wfc = (const float*)d_in[8];
    const float* bfc = (const float*)d_in[9];
    float* out = (float*)d_out;

    char* ws = (char*)d_ws;
    size_t off = 0;
    auto alloc = [&](size_t bytes) -> void* {
        void* p = ws + off;
        off = (off + bytes + 255) & ~(size_t)255;
        return p;
    };
    int*      zbuf   = (int*)     alloc((size_t)ZN * 4);   // cnt | bflag | bval
    int*      cnt    = zbuf;
    int*      bflag  = zbuf + 50176;
    int*      bval   = zbuf + 50176 + 256;
    int*      start  = (int*)     alloc((size_t)(N_NODES + 1) * 4);
    int*      cursor = (int*)     alloc((size_t)N_NODES * 4);
    uint4*    rec    = (uint4*)   alloc((size_t)N_EDGES * 32);
    unsigned* y      = (unsigned*)alloc((size_t)N_NODES * 256 * 2);
    float*    hbuf   = (float*)   alloc((size_t)N_NODES * 64 * 4);

    // co-residency-safe grid size
    int occ = 0;
    if (hipOccupancyMaxActiveBlocksPerMultiprocessor(&occ, fused_k, 256, 0) != hipSuccess || occ < 1)
        occ = 1;
    int grid = occ * 256;
    if (grid > 1024) grid = 1024;
    if (grid < 256) grid = 256;   // must cover NBLK=196 scan blocks

    void* args[] = { (void*)&nf, (void*)&ef, (void*)&src, (void*)&dst,
                     (void*)&W0, (void*)&b0, (void*)&W1, (void*)&b1,
                     (void*)&Wfc, (void*)&bfc, (void*)&out,
                     (void*)&cnt, (void*)&bflag, (void*)&bval, (void*)&start,
                     (void*)&cursor, (void*)&rec, (void*)&y, (void*)&hbuf };
    hipLaunchCooperativeKernel((const void*)fused_k, dim3(grid), dim3(256), args, 0, stream);
}

// Round 8
// 459.721 us; speedup vs baseline: 1.7058x; 1.7058x over previous
//
#include <hip/hip_runtime.h>
#include <hip/hip_fp16.h>

#define N_NODES 50000
#define N_EDGES 500000
#define DIM 64
#define KDIM 4
#define HID 64
#define NCLS 40
#define NBLK ((N_NODES + 255) / 256)   // 196
#define NGRP (N_NODES / 16)            // 3125 node-groups (exact)
#define NUNITS (782 * 2)               // 782 node-tiles x 2 k-pairs
// zbuf: cnt padded to 50176 | bar[8] | bflag[256] | bval[256]
#define ZN (50176 + 8 + 256 + 256)

__device__ inline unsigned pack2(float a, float b) {
    __half2 h = __floats2half2_rn(a, b);
    return *(unsigned*)&h;
}
__device__ inline float2 unpack2(unsigned u) {
    __half2 h = *(__half2*)&u;
    return __half22float2(h);
}

// ---- cheap grid barrier: ONE fence + ONE atomic per block ----
// requires all blocks co-resident (guaranteed by occupancy-clamped grid).
__device__ inline void gbar(int* bar, int t) {
    __syncthreads();
    if (t == 0) {
        __threadfence();                 // agent release: flush our dirty lines
        atomicAdd(bar, 1);
        while (__hip_atomic_load(bar, __ATOMIC_RELAXED, __HIP_MEMORY_SCOPE_AGENT)
               < (int)gridDim.x) {
            __builtin_amdgcn_s_sleep(8);
        }
        __threadfence();                 // agent acquire
    }
    __syncthreads();
}

// ---- transform tile unit: 64 nodes x 128 cols (one k-pair), fp16 W in LDS ----
// u = node_tile*2 + kpair. Per thread: 2 nodes x 16 cols.
__device__ inline void transform_unit(const float* __restrict__ hin,
                                      const float* __restrict__ W,
                                      unsigned* __restrict__ y,
                                      int u, int t, __half* sW, float* sh) {
    int nt = u >> 1;
    int kp = u & 1;
    __syncthreads();   // protect previous unit's LDS reads
    // stage W k-pair (8192 floats) as fp16: 2048 float4 / 256 thr = 8 each
    const float4* W4 = (const float4*)(W + (size_t)kp * 8192);
    __half2* sW2 = (__half2*)sW;
#pragma unroll
    for (int i = 0; i < 8; ++i) {
        int idx = t + 256 * i;
        float4 v = W4[idx];
        sW2[2 * idx]     = __floats2half2_rn(v.x, v.y);
        sW2[2 * idx + 1] = __floats2half2_rn(v.z, v.w);
    }
    // stage h tile: 64 nodes x 16 float4
    int n0 = nt * 64;
#pragma unroll
    for (int i = 0; i < 4; ++i) {
        int idx = t + 256 * i;
        int nl = idx >> 4;
        int dg = idx & 15;
        int n = n0 + nl;
        float4 v = make_float4(0.f, 0.f, 0.f, 0.f);
        if (n < N_NODES) v = ((const float4*)hin)[(size_t)n * 16 + dg];
        sh[nl * 65 + dg * 4 + 0] = v.x;
        sh[nl * 65 + dg * 4 + 1] = v.y;
        sh[nl * 65 + dg * 4 + 2] = v.z;
        sh[nl * 65 + dg * 4 + 3] = v.w;
    }
    __syncthreads();

    int nl = t & 31;
    int cg = t >> 5;              // 0..7
    int kl = cg >> 2;             // 0..1
    int hc0 = (cg & 3) * 16;

    float acc0[16], acc1[16];
#pragma unroll
    for (int j = 0; j < 16; ++j) { acc0[j] = 0.f; acc1[j] = 0.f; }

    for (int d = 0; d < 64; ++d) {
        float a0 = sh[nl * 65 + d];
        float a1 = sh[(nl + 32) * 65 + d];
        const __half2* wr = (const __half2*)(sW + kl * 4096 + d * 64 + hc0);
#pragma unroll
        for (int j = 0; j < 8; ++j) {
            float2 w2 = __half22float2(wr[j]);
            acc0[2 * j]     = fmaf(a0, w2.x, acc0[2 * j]);
            acc0[2 * j + 1] = fmaf(a0, w2.y, acc0[2 * j + 1]);
            acc1[2 * j]     = fmaf(a1, w2.x, acc1[2 * j]);
            acc1[2 * j + 1] = fmaf(a1, w2.y, acc1[2 * j + 1]);
        }
    }

    int n_a = n0 + nl, n_b = n0 + nl + 32;
    int cbase = (kp * 2 + kl) * 64 + hc0;
    if (n_a < N_NODES) {
        uint4* o = (uint4*)(y + ((size_t)n_a * 256 + cbase) / 2);
        o[0] = make_uint4(pack2(acc0[0], acc0[1]), pack2(acc0[2], acc0[3]),
                          pack2(acc0[4], acc0[5]), pack2(acc0[6], acc0[7]));
        o[1] = make_uint4(pack2(acc0[8], acc0[9]), pack2(acc0[10], acc0[11]),
                          pack2(acc0[12], acc0[13]), pack2(acc0[14], acc0[15]));
    }
    if (n_b < N_NODES) {
        uint4* o = (uint4*)(y + ((size_t)n_b * 256 + cbase) / 2);
        o[0] = make_uint4(pack2(acc1[0], acc1[1]), pack2(acc1[2], acc1[3]),
                          pack2(acc1[4], acc1[5]), pack2(acc1[6], acc1[7]));
        o[1] = make_uint4(pack2(acc1[8], acc1[9]), pack2(acc1[10], acc1[11]),
                          pack2(acc1[12], acc1[13]), pack2(acc1[14], acc1[15]));
    }
}

// ---- edge load/compute split for the per-edge MLP (fp16 y) ----
__device__ inline void load_edge(const uint4 r, const unsigned* __restrict__ y,
                                 int lane, uint2& q0, uint2& q1, uint2& q2, uint2& q3) {
    int sn = (int)r.x;
    const uint2* yb = (const uint2*)(y + (size_t)sn * 128);
    q0 = yb[lane];
    q1 = yb[16 + lane];
    q2 = yb[32 + lane];
    q3 = yb[48 + lane];
}

__device__ inline void compute_edge(const uint4 r, uint2 q0, uint2 q1, uint2 q2, uint2 q3,
                                    const float4 bias, float4& acc) {
    float2 e01 = unpack2(r.y);
    float2 e23 = unpack2(r.z);
    float2 a0 = unpack2(q0.x), a1 = unpack2(q0.y);
    float2 b0 = unpack2(q1.x), b1 = unpack2(q1.y);
    float2 c0 = unpack2(q2.x), c1 = unpack2(q2.y);
    float2 d0 = unpack2(q3.x), d1 = unpack2(q3.y);

    float4 z = bias;
    z.x = fmaf(e01.x, a0.x, z.x); z.y = fmaf(e01.x, a0.y, z.y);
    z.z = fmaf(e01.x, a1.x, z.z); z.w = fmaf(e01.x, a1.y, z.w);
    z.x = fmaf(e01.y, b0.x, z.x); z.y = fmaf(e01.y, b0.y, z.y);
    z.z = fmaf(e01.y, b1.x, z.z); z.w = fmaf(e01.y, b1.y, z.w);
    z.x = fmaf(e23.x, c0.x, z.x); z.y = fmaf(e23.x, c0.y, z.y);
    z.z = fmaf(e23.x, c1.x, z.z); z.w = fmaf(e23.x, c1.y, z.w);
    z.x = fmaf(e23.y, d0.x, z.x); z.y = fmaf(e23.y, d0.y, z.y);
    z.z = fmaf(e23.y, d1.x, z.z); z.w = fmaf(e23.y, d1.y, z.w);

    acc.x += fmaxf(z.x, 0.f);
    acc.y += fmaxf(z.y, 0.f);
    acc.z += fmaxf(z.z, 0.f);
    acc.w += fmaxf(z.w, 0.f);
}

// ---- aggregate core: unroll-4, batched loads; rec2 strided by 2 uint4 ----
__device__ inline float4 agg_core(const uint4* __restrict__ rec2,
                                  const int* __restrict__ start,
                                  const int* __restrict__ cnt,
                                  const unsigned* __restrict__ y,
                                  const float* __restrict__ b,
                                  int g, int lane) {
    int s0 = start[g];
    int deg = cnt[g];
    int s1 = s0 + deg;

    float4 bias = ((const float4*)b)[lane];
    float4 acc = make_float4(0.f, 0.f, 0.f, 0.f);

    int i = s0;
    for (; i + 4 <= s1; i += 4) {
        uint4 r0 = rec2[2 * i + 0];
        uint4 r1 = rec2[2 * i + 2];
        uint4 r2 = rec2[2 * i + 4];
        uint4 r3 = rec2[2 * i + 6];
        uint2 a0, a1, a2, a3, b0, b1, b2, b3, c0, c1, c2, c3, d0, d1, d2, d3;
        load_edge(r0, y, lane, a0, a1, a2, a3);
        load_edge(r1, y, lane, b0, b1, b2, b3);
        load_edge(r2, y, lane, c0, c1, c2, c3);
        load_edge(r3, y, lane, d0, d1, d2, d3);
        compute_edge(r0, a0, a1, a2, a3, bias, acc);
        compute_edge(r1, b0, b1, b2, b3, bias, acc);
        compute_edge(r2, c0, c1, c2, c3, bias, acc);
        compute_edge(r3, d0, d1, d2, d3, bias, acc);
    }
    if (i + 2 <= s1) {
        uint4 r0 = rec2[2 * i + 0];
        uint4 r1 = rec2[2 * i + 2];
        uint2 a0, a1, a2, a3, b0, b1, b2, b3;
        load_edge(r0, y, lane, a0, a1, a2, a3);
        load_edge(r1, y, lane, b0, b1, b2, b3);
        compute_edge(r0, a0, a1, a2, a3, bias, acc);
        compute_edge(r1, b0, b1, b2, b3, bias, acc);
        i += 2;
    }
    if (i < s1) {
        uint4 r0 = rec2[2 * i];
        uint2 a0, a1, a2, a3;
        load_edge(r0, y, lane, a0, a1, a2, a3);
        compute_edge(r0, a0, a1, a2, a3, bias, acc);
    }

    float inv = 1.0f / (float)(deg > 1 ? deg : 1);
    float4 r;
    r.x = fmaxf(acc.x * inv, 0.f);
    r.y = fmaxf(acc.y * inv, 0.f);
    r.z = fmaxf(acc.z * inv, 0.f);
    r.w = fmaxf(acc.w * inv, 0.f);
    return r;
}

// ---- K_a: transform layer-0 + dst histogram (independent work, no barrier) ----
__global__ __launch_bounds__(256, 4) void front_k(const float* __restrict__ nf,
                                                  const float* __restrict__ W0,
                                                  unsigned* __restrict__ y,
                                                  const int* __restrict__ dst,
                                                  int* __restrict__ cnt) {
    __shared__ __align__(16) char smem[33024];
    __half* sW = (__half*)smem;
    float* sh = (float*)(smem + 16384);
    int t = threadIdx.x;

    for (int u = blockIdx.x; u < NUNITS; u += gridDim.x)
        transform_unit(nf, W0, y, u, t, sW, sh);

    int gtid = blockIdx.x * 256 + t;
    int gth = gridDim.x * 256;
    for (int e = gtid; e < N_EDGES; e += gth) atomicAdd(&cnt[dst[e]], 1);
}

// ---- K_b: scan (lookback) + barrier + payload scatter. 196 blocks, co-resident ----
__global__ __launch_bounds__(256) void mid_k(const int* __restrict__ cnt,
                                             int* __restrict__ start,
                                             int* __restrict__ cursor,
                                             volatile int* __restrict__ bflag,
                                             volatile int* __restrict__ bval,
                                             int* __restrict__ bar0,
                                             const int* __restrict__ src,
                                             const int* __restrict__ dst,
                                             const float* __restrict__ ef,
                                             uint4* __restrict__ rec) {
    __shared__ int ls[258];
    int b = blockIdx.x, t = threadIdx.x;
    int n = b * 256 + t;
    int v = (n < N_NODES) ? cnt[n] : 0;
    ls[t] = v;
    __syncthreads();
#pragma unroll
    for (int off = 1; off < 256; off <<= 1) {
        int u = (t >= off) ? ls[t - off] : 0;
        __syncthreads();
        ls[t] += u;
        __syncthreads();
    }
    int incl = ls[t];
    int total = ls[255];
    __syncthreads();

    if (t == 0) {
        ((int*)bval)[b] = total;
        __threadfence();
        ((int*)bflag)[b] = 1;
    }

    if (b > 0) {
        for (;;) {
            int f = (t < b) ? bflag[t] : 1;
            if (t == 0) ls[256] = 1;
            __syncthreads();
            if (!f) ls[256] = 0;
            __syncthreads();
            if (ls[256]) break;
        }
        __threadfence();
        int pv = (t < b) ? bval[t] : 0;
        ls[t] = pv;
        __syncthreads();
#pragma unroll
        for (int off = 128; off > 0; off >>= 1) {
            if (t < off) ls[t] += ls[t + off];
            __syncthreads();
        }
        if (t == 0) ls[257] = ls[0];
        __syncthreads();
    } else {
        if (t == 0) ls[257] = 0;
        __syncthreads();
    }

    int excl = ls[257] + incl - v;
    if (n < N_NODES) { start[n] = excl; cursor[n] = excl; }
    if (n == 0) start[N_NODES] = N_EDGES;

    // barrier: all cursors globally visible before any scatter atomic
    gbar(bar0, t);

    int gtid = b * 256 + t;
    int gth = gridDim.x * 256;
    for (int e = gtid; e < N_EDGES; e += gth) {
        int d = dst[e];
        int pos = atomicAdd(&cursor[d], 1);
        int sn = src[e];
        float4 f0 = ((const float4*)ef)[e];
        float4 f1 = ((const float4*)ef)[N_EDGES + e];
        rec[2 * pos]     = make_uint4((unsigned)sn, pack2(f0.x, f0.y), pack2(f0.z, f0.w), 0u);
        rec[2 * pos + 1] = make_uint4((unsigned)sn, pack2(f1.x, f1.y), pack2(f1.z, f1.w), 0u);
    }
}

// ---- K_c: agg0 | bar | transform1 | bar | agg_fc ----
__global__ __launch_bounds__(256, 4) void back_k(const uint4* __restrict__ rec,
                                                 const int* __restrict__ start,
                                                 const int* __restrict__ cnt,
                                                 unsigned* __restrict__ y,
                                                 const float* __restrict__ b0,
                                                 const float* __restrict__ W1,
                                                 const float* __restrict__ b1,
                                                 const float* __restrict__ Wfc,
                                                 const float* __restrict__ bfc,
                                                 float* __restrict__ hbuf,
                                                 float* __restrict__ out,
                                                 int* __restrict__ bar1,
                                                 int* __restrict__ bar2) {
    __shared__ __align__(16) char smem[33024];
    int t = threadIdx.x;

    // phase A: aggregate layer 0 -> hbuf (fp32)
    {
        int nl = t >> 4;
        int lane = t & 15;
        for (int nb = blockIdx.x; nb < NGRP; nb += gridDim.x) {
            int g = nb * 16 + nl;
            float4 r = agg_core(rec, start, cnt, y, b0, g, lane);
            ((float4*)hbuf)[(size_t)g * 16 + lane] = r;
        }
    }
    gbar(bar1, t);

    // phase B: transform layer 1 -> y
    {
        __half* sW = (__half*)smem;
        float* sh = (float*)(smem + 16384);
        for (int u = blockIdx.x; u < NUNITS; u += gridDim.x)
            transform_unit(hbuf, W1, y, u, t, sW, sh);
    }
    gbar(bar2, t);

    // phase C: aggregate layer 1 + fused classifier
    {
        float* sh_h  = (float*)smem;                    // 16*65
        float* sWfcT = (float*)(smem + 4160);           // 40*65 transposed+padded
        float* sbfc  = (float*)(smem + 4160 + 10400);   // 40
        __syncthreads();   // LDS reuse guard
        for (int i = t; i < 64 * NCLS; i += 256) {
            int j = i / NCLS;
            int c = i - j * NCLS;
            sWfcT[c * 65 + j] = Wfc[i];
        }
        if (t < NCLS) sbfc[t] = bfc[t];
        __syncthreads();

        int nl = t >> 4;
        int lane = t & 15;
        for (int nb = blockIdx.x; nb < NGRP; nb += gridDim.x) {
            int g = nb * 16 + nl;
            float4 r = agg_core(rec + 1, start, cnt, y, b1, g, lane);
            sh_h[nl * 65 + lane * 4 + 0] = r.x;
            sh_h[nl * 65 + lane * 4 + 1] = r.y;
            sh_h[nl * 65 + lane * 4 + 2] = r.z;
            sh_h[nl * 65 + lane * 4 + 3] = r.w;
            __syncthreads();
            for (int item = t; item < 16 * NCLS; item += 256) {
                int rn = item / NCLS;
                int c = item - rn * NCLS;
                float acc = sbfc[c];
                const float* hr = &sh_h[rn * 65];
                const float* wc = &sWfcT[c * 65];
#pragma unroll
                for (int j = 0; j < 64; ++j) acc = fmaf(hr[j], wc[j], acc);
                out[(size_t)(nb * 16 + rn) * NCLS + c] = acc;
            }
            __syncthreads();
        }
    }
}

extern "C" void kernel_launch(void* const* d_in, const int* in_sizes, int n_in,
                              void* d_out, int out_size, void* d_ws, size_t ws_size,
                              hipStream_t stream) {
    const float* nf  = (const float*)d_in[0];
    const float* ef  = (const float*)d_in[1];
    const int*   src = (const int*)d_in[2];
    const int*   dst = (const int*)d_in[3];
    const float* W0  = (const float*)d_in[4];
    const float* b0  = (const float*)d_in[5];
    const float* W1  = (const float*)d_in[6];
    const float* b1  = (const float*)d_in[7];
    const float* Wfc = (const float*)d_in[8];
    const float* bfc = (const float*)d_in[9];
    float* out = (float*)d_out;

    char* ws = (char*)d_ws;
    size_t off = 0;
    auto alloc = [&](size_t bytes) -> void* {
        void* p = ws + off;
        off = (off + bytes + 255) & ~(size_t)255;
        return p;
    };
    int*      zbuf   = (int*)     alloc((size_t)ZN * 4);
    int*      cnt    = zbuf;                 // [50176]
    int*      bar    = zbuf + 50176;         // [8]  bar0,bar1,bar2
    int*      bflag  = zbuf + 50176 + 8;     // [256]
    int*      bval   = zbuf + 50176 + 8 + 256;
    int*      start  = (int*)     alloc((size_t)(N_NODES + 1) * 4);
    int*      cursor = (int*)     alloc((size_t)N_NODES * 4);
    uint4*    rec    = (uint4*)   alloc((size_t)N_EDGES * 32);
    unsigned* y      = (unsigned*)alloc((size_t)N_NODES * 256 * 2);
    float*    hbuf   = (float*)   alloc((size_t)N_NODES * 64 * 4);

    hipMemsetAsync(zbuf, 0, (size_t)ZN * 4, stream);

    front_k<<<1024, 256, 0, stream>>>(nf, W0, y, dst, cnt);
    mid_k<<<NBLK, 256, 0, stream>>>(cnt, start, cursor, bflag, bval, bar + 0,
                                    src, dst, ef, rec);

    int occ = 0;
    if (hipOccupancyMaxActiveBlocksPerMultiprocessor(&occ, back_k, 256, 0) != hipSuccess || occ < 1)
        occ = 1;
    if (occ > 4) occ = 4;
    int gridC = occ * 256;
    back_k<<<gridC, 256, 0, stream>>>(rec, start, cnt, y, b0, W1, b1, Wfc, bfc,
                                      hbuf, out, bar + 1, bar + 2);
}

// Round 10
// 326.235 us; speedup vs baseline: 2.4038x; 1.4092x over previous
//
#include <hip/hip_runtime.h>
#include <hip/hip_fp16.h>

#define N_NODES 50000
#define N_EDGES 500000
#define DIM 64
#define KDIM 4
#define HID 64
#define NCLS 40
#define NBLK ((N_NODES + 255) / 256)   // 196
#define NGRP (N_NODES / 16)            // 3125 (exact)
#define NUNITS (782 * 2)               // 782 node-tiles x 2 k-pairs
// zbuf: cnt padded to 50176 | bar[8] | bflag[256] | bval[256]
#define ZN (50176 + 8 + 256 + 256)

typedef unsigned nuint4 __attribute__((ext_vector_type(4)));

__device__ inline uint4 nt_load4(const uint4* p) {
    nuint4 v = __builtin_nontemporal_load((const nuint4*)p);
    return make_uint4(v.x, v.y, v.z, v.w);
}
__device__ inline void nt_store4(const uint4 v, uint4* p) {
    nuint4 w = { v.x, v.y, v.z, v.w };
    __builtin_nontemporal_store(w, (nuint4*)p);
}

__device__ inline unsigned pack2(float a, float b) {
    __half2 h = __floats2half2_rn(a, b);
    return *(unsigned*)&h;
}
__device__ inline float2 unpack2(unsigned u) {
    __half2 h = *(__half2*)&u;
    return __half22float2(h);
}

// ---- grid barrier (SMALL grids only: used by mid_k's 196 blocks) ----
__device__ inline void gbar(int* bar, int t) {
    __syncthreads();
    if (t == 0) {
        __threadfence();
        atomicAdd(bar, 1);
        while (__hip_atomic_load(bar, __ATOMIC_RELAXED, __HIP_MEMORY_SCOPE_AGENT)
               < (int)gridDim.x) {
            __builtin_amdgcn_s_sleep(8);
        }
        __threadfence();
    }
    __syncthreads();
}

// ---- transform tile unit: 64 nodes x 128 cols (one k-pair), fp16 W in LDS ----
__device__ inline void transform_unit(const float* __restrict__ hin,
                                      const float* __restrict__ W,
                                      unsigned* __restrict__ y,
                                      int u, int t, __half* sW, float* sh) {
    int nt = u >> 1;
    int kp = u & 1;
    __syncthreads();   // protect previous unit's LDS reads
    const float4* W4 = (const float4*)(W + (size_t)kp * 8192);
    __half2* sW2 = (__half2*)sW;
#pragma unroll
    for (int i = 0; i < 8; ++i) {
        int idx = t + 256 * i;
        float4 v = W4[idx];
        sW2[2 * idx]     = __floats2half2_rn(v.x, v.y);
        sW2[2 * idx + 1] = __floats2half2_rn(v.z, v.w);
    }
    int n0 = nt * 64;
#pragma unroll
    for (int i = 0; i < 4; ++i) {
        int idx = t + 256 * i;
        int nl = idx >> 4;
        int dg = idx & 15;
        int n = n0 + nl;
        float4 v = make_float4(0.f, 0.f, 0.f, 0.f);
        if (n < N_NODES) v = ((const float4*)hin)[(size_t)n * 16 + dg];
        sh[nl * 65 + dg * 4 + 0] = v.x;
        sh[nl * 65 + dg * 4 + 1] = v.y;
        sh[nl * 65 + dg * 4 + 2] = v.z;
        sh[nl * 65 + dg * 4 + 3] = v.w;
    }
    __syncthreads();

    int nl = t & 31;
    int cg = t >> 5;
    int kl = cg >> 2;
    int hc0 = (cg & 3) * 16;

    float acc0[16], acc1[16];
#pragma unroll
    for (int j = 0; j < 16; ++j) { acc0[j] = 0.f; acc1[j] = 0.f; }

    for (int d = 0; d < 64; ++d) {
        float a0 = sh[nl * 65 + d];
        float a1 = sh[(nl + 32) * 65 + d];
        const __half2* wr = (const __half2*)(sW + kl * 4096 + d * 64 + hc0);
#pragma unroll
        for (int j = 0; j < 8; ++j) {
            float2 w2 = __half22float2(wr[j]);
            acc0[2 * j]     = fmaf(a0, w2.x, acc0[2 * j]);
            acc0[2 * j + 1] = fmaf(a0, w2.y, acc0[2 * j + 1]);
            acc1[2 * j]     = fmaf(a1, w2.x, acc1[2 * j]);
            acc1[2 * j + 1] = fmaf(a1, w2.y, acc1[2 * j + 1]);
        }
    }

    int n_a = n0 + nl, n_b = n0 + nl + 32;
    int cbase = (kp * 2 + kl) * 64 + hc0;
    if (n_a < N_NODES) {
        uint4* o = (uint4*)(y + ((size_t)n_a * 256 + cbase) / 2);
        o[0] = make_uint4(pack2(acc0[0], acc0[1]), pack2(acc0[2], acc0[3]),
                          pack2(acc0[4], acc0[5]), pack2(acc0[6], acc0[7]));
        o[1] = make_uint4(pack2(acc0[8], acc0[9]), pack2(acc0[10], acc0[11]),
                          pack2(acc0[12], acc0[13]), pack2(acc0[14], acc0[15]));
    }
    if (n_b < N_NODES) {
        uint4* o = (uint4*)(y + ((size_t)n_b * 256 + cbase) / 2);
        o[0] = make_uint4(pack2(acc1[0], acc1[1]), pack2(acc1[2], acc1[3]),
                          pack2(acc1[4], acc1[5]), pack2(acc1[6], acc1[7]));
        o[1] = make_uint4(pack2(acc1[8], acc1[9]), pack2(acc1[10], acc1[11]),
                          pack2(acc1[12], acc1[13]), pack2(acc1[14], acc1[15]));
    }
}

// ---- edge load/compute for the per-edge MLP (fp16 y) ----
__device__ inline void load_edge(const uint4 r, const unsigned* __restrict__ y,
                                 int lane, uint2& q0, uint2& q1, uint2& q2, uint2& q3) {
    int sn = (int)r.x;
    const uint2* yb = (const uint2*)(y + (size_t)sn * 128);
    q0 = yb[lane];
    q1 = yb[16 + lane];
    q2 = yb[32 + lane];
    q3 = yb[48 + lane];
}

__device__ inline void compute_edge(const uint4 r, uint2 q0, uint2 q1, uint2 q2, uint2 q3,
                                    const float4 bias, float4& acc) {
    float2 e01 = unpack2(r.y);
    float2 e23 = unpack2(r.z);
    float2 a0 = unpack2(q0.x), a1 = unpack2(q0.y);
    float2 b0 = unpack2(q1.x), b1 = unpack2(q1.y);
    float2 c0 = unpack2(q2.x), c1 = unpack2(q2.y);
    float2 d0 = unpack2(q3.x), d1 = unpack2(q3.y);

    float4 z = bias;
    z.x = fmaf(e01.x, a0.x, z.x); z.y = fmaf(e01.x, a0.y, z.y);
    z.z = fmaf(e01.x, a1.x, z.z); z.w = fmaf(e01.x, a1.y, z.w);
    z.x = fmaf(e01.y, b0.x, z.x); z.y = fmaf(e01.y, b0.y, z.y);
    z.z = fmaf(e01.y, b1.x, z.z); z.w = fmaf(e01.y, b1.y, z.w);
    z.x = fmaf(e23.x, c0.x, z.x); z.y = fmaf(e23.x, c0.y, z.y);
    z.z = fmaf(e23.x, c1.x, z.z); z.w = fmaf(e23.x, c1.y, z.w);
    z.x = fmaf(e23.y, d0.x, z.x); z.y = fmaf(e23.y, d0.y, z.y);
    z.z = fmaf(e23.y, d1.x, z.z); z.w = fmaf(e23.y, d1.y, z.w);

    acc.x += fmaxf(z.x, 0.f);
    acc.y += fmaxf(z.y, 0.f);
    acc.z += fmaxf(z.z, 0.f);
    acc.w += fmaxf(z.w, 0.f);
}

// ---- aggregate core: unroll-4, batched loads, nontemporal rec stream ----
__device__ inline float4 agg_core(const uint4* __restrict__ rec2,
                                  const int* __restrict__ start,
                                  const int* __restrict__ cnt,
                                  const unsigned* __restrict__ y,
                                  const float* __restrict__ b,
                                  int g, int lane) {
    int s0 = start[g];
    int deg = cnt[g];
    int s1 = s0 + deg;

    float4 bias = ((const float4*)b)[lane];
    float4 acc = make_float4(0.f, 0.f, 0.f, 0.f);

    int i = s0;
    for (; i + 4 <= s1; i += 4) {
        uint4 r0 = nt_load4(&rec2[2 * i + 0]);
        uint4 r1 = nt_load4(&rec2[2 * i + 2]);
        uint4 r2 = nt_load4(&rec2[2 * i + 4]);
        uint4 r3 = nt_load4(&rec2[2 * i + 6]);
        uint2 a0, a1, a2, a3, b0, b1, b2, b3, c0, c1, c2, c3, d0, d1, d2, d3;
        load_edge(r0, y, lane, a0, a1, a2, a3);
        load_edge(r1, y, lane, b0, b1, b2, b3);
        load_edge(r2, y, lane, c0, c1, c2, c3);
        load_edge(r3, y, lane, d0, d1, d2, d3);
        compute_edge(r0, a0, a1, a2, a3, bias, acc);
        compute_edge(r1, b0, b1, b2, b3, bias, acc);
        compute_edge(r2, c0, c1, c2, c3, bias, acc);
        compute_edge(r3, d0, d1, d2, d3, bias, acc);
    }
    if (i + 2 <= s1) {
        uint4 r0 = nt_load4(&rec2[2 * i + 0]);
        uint4 r1 = nt_load4(&rec2[2 * i + 2]);
        uint2 a0, a1, a2, a3, b0, b1, b2, b3;
        load_edge(r0, y, lane, a0, a1, a2, a3);
        load_edge(r1, y, lane, b0, b1, b2, b3);
        compute_edge(r0, a0, a1, a2, a3, bias, acc);
        compute_edge(r1, b0, b1, b2, b3, bias, acc);
        i += 2;
    }
    if (i < s1) {
        uint4 r0 = nt_load4(&rec2[2 * i]);
        uint2 a0, a1, a2, a3;
        load_edge(r0, y, lane, a0, a1, a2, a3);
        compute_edge(r0, a0, a1, a2, a3, bias, acc);
    }

    float inv = 1.0f / (float)(deg > 1 ? deg : 1);
    float4 r;
    r.x = fmaxf(acc.x * inv, 0.f);
    r.y = fmaxf(acc.y * inv, 0.f);
    r.z = fmaxf(acc.z * inv, 0.f);
    r.w = fmaxf(acc.w * inv, 0.f);
    return r;
}

// ---- K1: transform layer-0 + dst histogram (independent, no barrier) ----
__global__ __launch_bounds__(256, 4) void front_k(const float* __restrict__ nf,
                                                  const float* __restrict__ W0,
                                                  unsigned* __restrict__ y,
                                                  const int* __restrict__ dst,
                                                  int* __restrict__ cnt) {
    __shared__ __align__(16) char smem[33024];
    __half* sW = (__half*)smem;
    float* sh = (float*)(smem + 16384);
    int t = threadIdx.x;

    for (int u = blockIdx.x; u < NUNITS; u += gridDim.x)
        transform_unit(nf, W0, y, u, t, sW, sh);

    int gtid = blockIdx.x * 256 + t;
    int gth = gridDim.x * 256;
    for (int e = gtid; e < N_EDGES; e += gth) atomicAdd(&cnt[dst[e]], 1);
}

// ---- K2: scan (lookback) + small-grid barrier + payload scatter ----
__global__ __launch_bounds__(256) void mid_k(const int* __restrict__ cnt,
                                             int* __restrict__ start,
                                             int* __restrict__ cursor,
                                             volatile int* __restrict__ bflag,
                                             volatile int* __restrict__ bval,
                                             int* __restrict__ bar0,
                                             const int* __restrict__ src,
                                             const int* __restrict__ dst,
                                             const float* __restrict__ ef,
                                             uint4* __restrict__ rec) {
    __shared__ int ls[258];
    int b = blockIdx.x, t = threadIdx.x;
    int n = b * 256 + t;
    int v = (n < N_NODES) ? cnt[n] : 0;
    ls[t] = v;
    __syncthreads();
#pragma unroll
    for (int off = 1; off < 256; off <<= 1) {
        int u = (t >= off) ? ls[t - off] : 0;
        __syncthreads();
        ls[t] += u;
        __syncthreads();
    }
    int incl = ls[t];
    int total = ls[255];
    __syncthreads();

    if (t == 0) {
        ((int*)bval)[b] = total;
        __threadfence();
        ((int*)bflag)[b] = 1;
    }

    if (b > 0) {
        for (;;) {
            int f = (t < b) ? bflag[t] : 1;
            if (t == 0) ls[256] = 1;
            __syncthreads();
            if (!f) ls[256] = 0;
            __syncthreads();
            if (ls[256]) break;
        }
        __threadfence();
        int pv = (t < b) ? bval[t] : 0;
        ls[t] = pv;
        __syncthreads();
#pragma unroll
        for (int off = 128; off > 0; off >>= 1) {
            if (t < off) ls[t] += ls[t + off];
            __syncthreads();
        }
        if (t == 0) ls[257] = ls[0];
        __syncthreads();
    } else {
        if (t == 0) ls[257] = 0;
        __syncthreads();
    }

    int excl = ls[257] + incl - v;
    if (n < N_NODES) { start[n] = excl; cursor[n] = excl; }
    if (n == 0) start[N_NODES] = N_EDGES;

    gbar(bar0, t);   // 196 blocks only — proven cheap

    int gtid = b * 256 + t;
    int gth = gridDim.x * 256;
    for (int e = gtid; e < N_EDGES; e += gth) {
        int d = dst[e];
        int pos = atomicAdd(&cursor[d], 1);
        int sn = src[e];
        float4 f0 = ((const float4*)ef)[e];
        float4 f1 = ((const float4*)ef)[N_EDGES + e];
        nt_store4(make_uint4((unsigned)sn, pack2(f0.x, f0.y), pack2(f0.z, f0.w), 0u),
                  &rec[2 * pos]);
        nt_store4(make_uint4((unsigned)sn, pack2(f1.x, f1.y), pack2(f1.z, f1.w), 0u),
                  &rec[2 * pos + 1]);
    }
}

// ---- K3: aggregate layer 0 -> hbuf ----
__global__ __launch_bounds__(256) void agg_k(const uint4* __restrict__ rec,
                                             const int* __restrict__ start,
                                             const int* __restrict__ cnt,
                                             const unsigned* __restrict__ y,
                                             const float* __restrict__ b0,
                                             float* __restrict__ hbuf) {
    int t = blockIdx.x * 256 + threadIdx.x;
    int g = t >> 4;
    int lane = t & 15;
    float4 r = agg_core(rec, start, cnt, y, b0, g, lane);
    ((float4*)hbuf)[(size_t)g * 16 + lane] = r;
}

// ---- K4: transform layer 1 ----
__global__ __launch_bounds__(256, 4) void tr1_k(const float* __restrict__ hbuf,
                                                const float* __restrict__ W1,
                                                unsigned* __restrict__ y) {
    __shared__ __align__(16) char smem[33024];
    __half* sW = (__half*)smem;
    float* sh = (float*)(smem + 16384);
    int t = threadIdx.x;
    for (int u = blockIdx.x; u < NUNITS; u += gridDim.x)
        transform_unit(hbuf, W1, y, u, t, sW, sh);
}

// ---- K5: aggregate layer 1 + fused classifier ----
__global__ __launch_bounds__(256) void agg_fc_k(const uint4* __restrict__ rec,
                                                const int* __restrict__ start,
                                                const int* __restrict__ cnt,
                                                const unsigned* __restrict__ y,
                                                const float* __restrict__ b1,
                                                const float* __restrict__ Wfc,
                                                const float* __restrict__ bfc,
                                                float* __restrict__ out) {
    __shared__ float sh_h[16 * 65];
    __shared__ float sWfcT[NCLS * 65];
    __shared__ float sbfc[NCLS];
    int t = threadIdx.x;

    for (int i = t; i < 64 * NCLS; i += 256) {
        int j = i / NCLS;
        int c = i - j * NCLS;
        sWfcT[c * 65 + j] = Wfc[i];
    }
    if (t < NCLS) sbfc[t] = bfc[t];

    int nl = t >> 4;
    int lane = t & 15;
    int g = blockIdx.x * 16 + nl;

    float4 r = agg_core(rec, start, cnt, y, b1, g, lane);
    sh_h[nl * 65 + lane * 4 + 0] = r.x;
    sh_h[nl * 65 + lane * 4 + 1] = r.y;
    sh_h[nl * 65 + lane * 4 + 2] = r.z;
    sh_h[nl * 65 + lane * 4 + 3] = r.w;
    __syncthreads();

    for (int item = t; item < 16 * NCLS; item += 256) {
        int rn = item / NCLS;
        int c = item - rn * NCLS;
        float acc = sbfc[c];
        const float* hr = &sh_h[rn * 65];
        const float* wc = &sWfcT[c * 65];
#pragma unroll
        for (int j = 0; j < 64; ++j) acc = fmaf(hr[j], wc[j], acc);
        __builtin_nontemporal_store(acc, &out[(size_t)(blockIdx.x * 16 + rn) * NCLS + c]);
    }
}

extern "C" void kernel_launch(void* const* d_in, const int* in_sizes, int n_in,
                              void* d_out, int out_size, void* d_ws, size_t ws_size,
                              hipStream_t stream) {
    const float* nf  = (const float*)d_in[0];
    const float* ef  = (const float*)d_in[1];
    const int*   src = (const int*)d_in[2];
    const int*   dst = (const int*)d_in[3];
    const float* W0  = (const float*)d_in[4];
    const float* b0  = (const float*)d_in[5];
    const float* W1  = (const float*)d_in[6];
    const float* b1  = (const float*)d_in[7];
    const float* Wfc = (const float*)d_in[8];
    const float* bfc = (const float*)d_in[9];
    float* out = (float*)d_out;

    char* ws = (char*)d_ws;
    size_t off = 0;
    auto alloc = [&](size_t bytes) -> void* {
        void* p = ws + off;
        off = (off + bytes + 255) & ~(size_t)255;
        return p;
    };
    int*      zbuf   = (int*)     alloc((size_t)ZN * 4);
    int*      cnt    = zbuf;                 // [50176]
    int*      bar    = zbuf + 50176;         // [8]
    int*      bflag  = zbuf + 50176 + 8;     // [256]
    int*      bval   = zbuf + 50176 + 8 + 256;
    int*      start  = (int*)     alloc((size_t)(N_NODES + 1) * 4);
    int*      cursor = (int*)     alloc((size_t)N_NODES * 4);
    uint4*    rec    = (uint4*)   alloc((size_t)N_EDGES * 32);
    unsigned* y      = (unsigned*)alloc((size_t)N_NODES * 256 * 2);
    float*    hbuf   = (float*)   alloc((size_t)N_NODES * 64 * 4);

    (void)hipMemsetAsync(zbuf, 0, (size_t)ZN * 4, stream);

    front_k<<<1024, 256, 0, stream>>>(nf, W0, y, dst, cnt);
    mid_k<<<NBLK, 256, 0, stream>>>(cnt, start, cursor, bflag, bval, bar + 0,
                                    src, dst, ef, rec);
    agg_k<<<NGRP, 256, 0, stream>>>(rec, start, cnt, y, b0, hbuf);
    tr1_k<<<NUNITS, 256, 0, stream>>>(hbuf, W1, y);
    agg_fc_k<<<NGRP, 256, 0, stream>>>(rec + 1, start, cnt, y, b1, Wfc, bfc, out);
}

// Round 14
// 302.061 us; speedup vs baseline: 2.5962x; 1.0800x over previous
//
#include <hip/hip_runtime.h>
#include <hip/hip_fp16.h>

#define N_NODES 50000
#define N_EDGES 500000
#define DIM 64
#define KDIM 4
#define HID 64
#define NCLS 40
#define NBLK ((N_NODES + 255) / 256)   // 196
#define NGRP (N_NODES / 16)            // 3125 (exact)
#define NUNITS (782 * 2)               // 782 node-tiles x 2 k-pairs

typedef unsigned nuint4 __attribute__((ext_vector_type(4)));

__device__ inline uint4 nt_load4(const uint4* p) {
    nuint4 v = __builtin_nontemporal_load((const nuint4*)p);
    return make_uint4(v.x, v.y, v.z, v.w);
}
__device__ inline void nt_store4(const uint4 v, uint4* p) {
    nuint4 w = { v.x, v.y, v.z, v.w };
    __builtin_nontemporal_store(w, (nuint4*)p);
}

__device__ inline unsigned pack2(float a, float b) {
    __half2 h = __floats2half2_rn(a, b);
    return *(unsigned*)&h;
}
__device__ inline float2 unpack2(unsigned u) {
    __half2 h = *(__half2*)&u;
    return __half22float2(h);
}

// ---- transform tile unit: 64 nodes x 128 cols (one k-pair), fp16 W in LDS ----
__device__ inline void transform_unit(const float* __restrict__ hin,
                                      const float* __restrict__ W,
                                      unsigned* __restrict__ y,
                                      int u, int t, __half* sW, float* sh) {
    int nt = u >> 1;
    int kp = u & 1;
    __syncthreads();   // protect previous unit's LDS reads
    const float4* W4 = (const float4*)(W + (size_t)kp * 8192);
    __half2* sW2 = (__half2*)sW;
#pragma unroll
    for (int i = 0; i < 8; ++i) {
        int idx = t + 256 * i;
        float4 v = W4[idx];
        sW2[2 * idx]     = __floats2half2_rn(v.x, v.y);
        sW2[2 * idx + 1] = __floats2half2_rn(v.z, v.w);
    }
    int n0 = nt * 64;
#pragma unroll
    for (int i = 0; i < 4; ++i) {
        int idx = t + 256 * i;
        int nl = idx >> 4;
        int dg = idx & 15;
        int n = n0 + nl;
        float4 v = make_float4(0.f, 0.f, 0.f, 0.f);
        if (n < N_NODES) v = ((const float4*)hin)[(size_t)n * 16 + dg];
        sh[nl * 65 + dg * 4 + 0] = v.x;
        sh[nl * 65 + dg * 4 + 1] = v.y;
        sh[nl * 65 + dg * 4 + 2] = v.z;
        sh[nl * 65 + dg * 4 + 3] = v.w;
    }
    __syncthreads();

    int nl = t & 31;
    int cg = t >> 5;
    int kl = cg >> 2;
    int hc0 = (cg & 3) * 16;

    float acc0[16], acc1[16];
#pragma unroll
    for (int j = 0; j < 16; ++j) { acc0[j] = 0.f; acc1[j] = 0.f; }

    for (int d = 0; d < 64; ++d) {
        float a0 = sh[nl * 65 + d];
        float a1 = sh[(nl + 32) * 65 + d];
        const __half2* wr = (const __half2*)(sW + kl * 4096 + d * 64 + hc0);
#pragma unroll
        for (int j = 0; j < 8; ++j) {
            float2 w2 = __half22float2(wr[j]);
            acc0[2 * j]     = fmaf(a0, w2.x, acc0[2 * j]);
            acc0[2 * j + 1] = fmaf(a0, w2.y, acc0[2 * j + 1]);
            acc1[2 * j]     = fmaf(a1, w2.x, acc1[2 * j]);
            acc1[2 * j + 1] = fmaf(a1, w2.y, acc1[2 * j + 1]);
        }
    }

    int n_a = n0 + nl, n_b = n0 + nl + 32;
    int cbase = (kp * 2 + kl) * 64 + hc0;
    if (n_a < N_NODES) {
        uint4* o = (uint4*)(y + ((size_t)n_a * 256 + cbase) / 2);
        o[0] = make_uint4(pack2(acc0[0], acc0[1]), pack2(acc0[2], acc0[3]),
                          pack2(acc0[4], acc0[5]), pack2(acc0[6], acc0[7]));
        o[1] = make_uint4(pack2(acc0[8], acc0[9]), pack2(acc0[10], acc0[11]),
                          pack2(acc0[12], acc0[13]), pack2(acc0[14], acc0[15]));
    }
    if (n_b < N_NODES) {
        uint4* o = (uint4*)(y + ((size_t)n_b * 256 + cbase) / 2);
        o[0] = make_uint4(pack2(acc1[0], acc1[1]), pack2(acc1[2], acc1[3]),
                          pack2(acc1[4], acc1[5]), pack2(acc1[6], acc1[7]));
        o[1] = make_uint4(pack2(acc1[8], acc1[9]), pack2(acc1[10], acc1[11]),
                          pack2(acc1[12], acc1[13]), pack2(acc1[14], acc1[15]));
    }
}

// ---- edge load/compute for the per-edge MLP (fp16 y) ----
__device__ inline void load_edge(const uint4 r, const unsigned* __restrict__ y,
                                 int lane, uint2& q0, uint2& q1, uint2& q2, uint2& q3) {
    int sn = (int)r.x;
    const uint2* yb = (const uint2*)(y + (size_t)sn * 128);
    q0 = yb[lane];
    q1 = yb[16 + lane];
    q2 = yb[32 + lane];
    q3 = yb[48 + lane];
}

__device__ inline void compute_edge(const uint4 r, uint2 q0, uint2 q1, uint2 q2, uint2 q3,
                                    const float4 bias, float4& acc) {
    float2 e01 = unpack2(r.y);
    float2 e23 = unpack2(r.z);
    float2 a0 = unpack2(q0.x), a1 = unpack2(q0.y);
    float2 b0 = unpack2(q1.x), b1 = unpack2(q1.y);
    float2 c0 = unpack2(q2.x), c1 = unpack2(q2.y);
    float2 d0 = unpack2(q3.x), d1 = unpack2(q3.y);

    float4 z = bias;
    z.x = fmaf(e01.x, a0.x, z.x); z.y = fmaf(e01.x, a0.y, z.y);
    z.z = fmaf(e01.x, a1.x, z.z); z.w = fmaf(e01.x, a1.y, z.w);
    z.x = fmaf(e01.y, b0.x, z.x); z.y = fmaf(e01.y, b0.y, z.y);
    z.z = fmaf(e01.y, b1.x, z.z); z.w = fmaf(e01.y, b1.y, z.w);
    z.x = fmaf(e23.x, c0.x, z.x); z.y = fmaf(e23.x, c0.y, z.y);
    z.z = fmaf(e23.x, c1.x, z.z); z.w = fmaf(e23.x, c1.y, z.w);
    z.x = fmaf(e23.y, d0.x, z.x); z.y = fmaf(e23.y, d0.y, z.y);
    z.z = fmaf(e23.y, d1.x, z.z); z.w = fmaf(e23.y, d1.y, z.w);

    acc.x += fmaxf(z.x, 0.f);
    acc.y += fmaxf(z.y, 0.f);
    acc.z += fmaxf(z.z, 0.f);
    acc.w += fmaxf(z.w, 0.f);
}

// ---- aggregate core: unroll-4, batched loads, nontemporal rec stream ----
__device__ inline float4 agg_core(const uint4* __restrict__ rec2,
                                  const int* __restrict__ start,
                                  const int* __restrict__ cnt,
                                  const unsigned* __restrict__ y,
                                  const float* __restrict__ b,
                                  int g, int lane) {
    int s0 = start[g];
    int deg = cnt[g];
    int s1 = s0 + deg;

    float4 bias = ((const float4*)b)[lane];
    float4 acc = make_float4(0.f, 0.f, 0.f, 0.f);

    int i = s0;
    for (; i + 4 <= s1; i += 4) {
        uint4 r0 = nt_load4(&rec2[2 * i + 0]);
        uint4 r1 = nt_load4(&rec2[2 * i + 2]);
        uint4 r2 = nt_load4(&rec2[2 * i + 4]);
        uint4 r3 = nt_load4(&rec2[2 * i + 6]);
        uint2 a0, a1, a2, a3, b0, b1, b2, b3, c0, c1, c2, c3, d0, d1, d2, d3;
        load_edge(r0, y, lane, a0, a1, a2, a3);
        load_edge(r1, y, lane, b0, b1, b2, b3);
        load_edge(r2, y, lane, c0, c1, c2, c3);
        load_edge(r3, y, lane, d0, d1, d2, d3);
        compute_edge(r0, a0, a1, a2, a3, bias, acc);
        compute_edge(r1, b0, b1, b2, b3, bias, acc);
        compute_edge(r2, c0, c1, c2, c3, bias, acc);
        compute_edge(r3, d0, d1, d2, d3, bias, acc);
    }
    if (i + 2 <= s1) {
        uint4 r0 = nt_load4(&rec2[2 * i + 0]);
        uint4 r1 = nt_load4(&rec2[2 * i + 2]);
        uint2 a0, a1, a2, a3, b0, b1, b2, b3;
        load_edge(r0, y, lane, a0, a1, a2, a3);
        load_edge(r1, y, lane, b0, b1, b2, b3);
        compute_edge(r0, a0, a1, a2, a3, bias, acc);
        compute_edge(r1, b0, b1, b2, b3, bias, acc);
        i += 2;
    }
    if (i < s1) {
        uint4 r0 = nt_load4(&rec2[2 * i]);
        uint2 a0, a1, a2, a3;
        load_edge(r0, y, lane, a0, a1, a2, a3);
        compute_edge(r0, a0, a1, a2, a3, bias, acc);
    }

    float inv = 1.0f / (float)(deg > 1 ? deg : 1);
    float4 r;
    r.x = fmaxf(acc.x * inv, 0.f);
    r.y = fmaxf(acc.y * inv, 0.f);
    r.z = fmaxf(acc.z * inv, 0.f);
    r.w = fmaxf(acc.w * inv, 0.f);
    return r;
}

// ---- K1: transform layer-0 + dst histogram (independent work) ----
__global__ __launch_bounds__(256, 4) void front_k(const float* __restrict__ nf,
                                                  const float* __restrict__ W0,
                                                  unsigned* __restrict__ y,
                                                  const int* __restrict__ dst,
                                                  int* __restrict__ cnt) {
    __shared__ __align__(16) char smem[33024];
    __half* sW = (__half*)smem;
    float* sh = (float*)(smem + 16384);
    int t = threadIdx.x;

    for (int u = blockIdx.x; u < NUNITS; u += gridDim.x)
        transform_unit(nf, W0, y, u, t, sW, sh);

    int gtid = blockIdx.x * 256 + t;
    int gth = gridDim.x * 256;
    for (int e = gtid; e < N_EDGES; e += gth) atomicAdd(&cnt[dst[e]], 1);
}

// ---- K2a: per-block scan + block sums (no spin loops anywhere) ----
__global__ __launch_bounds__(256) void blk_scan_k(const int* __restrict__ cnt,
                                                  int* __restrict__ esc,
                                                  int* __restrict__ bsum) {
    __shared__ int ls[256];
    int t = threadIdx.x;
    int n = blockIdx.x * 256 + t;
    int v = (n < N_NODES) ? cnt[n] : 0;
    ls[t] = v;
    __syncthreads();
#pragma unroll
    for (int off = 1; off < 256; off <<= 1) {
        int u = (t >= off) ? ls[t - off] : 0;
        __syncthreads();
        ls[t] += u;
        __syncthreads();
    }
    if (n < N_NODES) esc[n] = ls[t] - v;
    if (t == 255) bsum[blockIdx.x] = ls[255];
}

// ---- K2b: scan the 196 block sums (single block) ----
__global__ __launch_bounds__(256) void bsum_scan_k(const int* __restrict__ bsum,
                                                   int* __restrict__ boff,
                                                   int* __restrict__ start) {
    __shared__ int ls[256];
    int t = threadIdx.x;
    int v = (t < NBLK) ? bsum[t] : 0;
    ls[t] = v;
    __syncthreads();
#pragma unroll
    for (int off = 1; off < 256; off <<= 1) {
        int u = (t >= off) ? ls[t - off] : 0;
        __syncthreads();
        ls[t] += u;
        __syncthreads();
    }
    if (t < NBLK) boff[t] = ls[t] - v;
    if (t == 0) start[N_NODES] = N_EDGES;
}

// ---- K2c: finalize start/cursor ----
__global__ void finalize_k(const int* __restrict__ esc, const int* __restrict__ boff,
                           int* __restrict__ start, int* __restrict__ cursor) {
    int n = blockIdx.x * 256 + threadIdx.x;
    if (n < N_NODES) {
        int s = esc[n] + boff[blockIdx.x];
        start[n] = s;
        cursor[n] = s;
    }
}

// ---- K3: counting-sort payload scatter (full 1954-block grid) ----
__global__ void scatter_k(const int* __restrict__ src, const int* __restrict__ dst,
                          const float* __restrict__ ef, int* __restrict__ cursor,
                          uint4* __restrict__ rec) {
    int e = blockIdx.x * 256 + threadIdx.x;
    if (e < N_EDGES) {
        int d = dst[e];
        int pos = atomicAdd(&cursor[d], 1);
        int sn = src[e];
        float4 f0 = ((const float4*)ef)[e];
        float4 f1 = ((const float4*)ef)[N_EDGES + e];
        nt_store4(make_uint4((unsigned)sn, pack2(f0.x, f0.y), pack2(f0.z, f0.w), 0u),
                  &rec[2 * pos]);
        nt_store4(make_uint4((unsigned)sn, pack2(f1.x, f1.y), pack2(f1.z, f1.w), 0u),
                  &rec[2 * pos + 1]);
    }
}

// ---- K4: aggregate layer 0 -> hbuf ----
__global__ __launch_bounds__(256) void agg_k(const uint4* __restrict__ rec,
                                             const int* __restrict__ start,
                                             const int* __restrict__ cnt,
                                             const unsigned* __restrict__ y,
                                             const float* __restrict__ b0,
                                             float* __restrict__ hbuf) {
    int t = blockIdx.x * 256 + threadIdx.x;
    int g = t >> 4;
    int lane = t & 15;
    float4 r = agg_core(rec, start, cnt, y, b0, g, lane);
    ((float4*)hbuf)[(size_t)g * 16 + lane] = r;
}

// ---- K5: transform layer 1 ----
__global__ __launch_bounds__(256, 4) void tr1_k(const float* __restrict__ hbuf,
                                                const float* __restrict__ W1,
                                                unsigned* __restrict__ y) {
    __shared__ __align__(16) char smem[33024];
    __half* sW = (__half*)smem;
    float* sh = (float*)(smem + 16384);
    int t = threadIdx.x;
    for (int u = blockIdx.x; u < NUNITS; u += gridDim.x)
        transform_unit(hbuf, W1, y, u, t, sW, sh);
}

// ---- K6: aggregate layer 1 + fused classifier ----
__global__ __launch_bounds__(256) void agg_fc_k(const uint4* __restrict__ rec,
                                                const int* __restrict__ start,
                                                const int* __restrict__ cnt,
                                                const unsigned* __restrict__ y,
                                                const float* __restrict__ b1,
                                                const float* __restrict__ Wfc,
                                                const float* __restrict__ bfc,
                                                float* __restrict__ out) {
    __shared__ float sh_h[16 * 65];
    __shared__ float sWfcT[NCLS * 65];
    __shared__ float sbfc[NCLS];
    int t = threadIdx.x;

    for (int i = t; i < 64 * NCLS; i += 256) {
        int j = i / NCLS;
        int c = i - j * NCLS;
        sWfcT[c * 65 + j] = Wfc[i];
    }
    if (t < NCLS) sbfc[t] = bfc[t];

    int nl = t >> 4;
    int lane = t & 15;
    int g = blockIdx.x * 16 + nl;

    float4 r = agg_core(rec, start, cnt, y, b1, g, lane);
    sh_h[nl * 65 + lane * 4 + 0] = r.x;
    sh_h[nl * 65 + lane * 4 + 1] = r.y;
    sh_h[nl * 65 + lane * 4 + 2] = r.z;
    sh_h[nl * 65 + lane * 4 + 3] = r.w;
    __syncthreads();

    for (int item = t; item < 16 * NCLS; item += 256) {
        int rn = item / NCLS;
        int c = item - rn * NCLS;
        float acc = sbfc[c];
        const float* hr = &sh_h[rn * 65];
        const float* wc = &sWfcT[c * 65];
#pragma unroll
        for (int j = 0; j < 64; ++j) acc = fmaf(hr[j], wc[j], acc);
        __builtin_nontemporal_store(acc, &out[(size_t)(blockIdx.x * 16 + rn) * NCLS + c]);
    }
}

extern "C" void kernel_launch(void* const* d_in, const int* in_sizes, int n_in,
                              void* d_out, int out_size, void* d_ws, size_t ws_size,
                              hipStream_t stream) {
    const float* nf  = (const float*)d_in[0];
    const float* ef  = (const float*)d_in[1];
    const int*   src = (const int*)d_in[2];
    const int*   dst = (const int*)d_in[3];
    const float* W0  = (const float*)d_in[4];
    const float* b0  = (const float*)d_in[5];
    const float* W1  = (const float*)d_in[6];
    const float* b1  = (const float*)d_in[7];
    const float* Wfc = (const float*)d_in[8];
    const float* bfc = (const float*)d_in[9];
    float* out = (float*)d_out;

    char* ws = (char*)d_ws;
    size_t off = 0;
    auto alloc = [&](size_t bytes) -> void* {
        void* p = ws + off;
        off = (off + bytes + 255) & ~(size_t)255;
        return p;
    };
    int*      cnt    = (int*)     alloc((size_t)N_NODES * 4);
    int*      esc    = (int*)     alloc((size_t)N_NODES * 4);
    int*      bsum   = (int*)     alloc((size_t)NBLK * 4);
    int*      boff   = (int*)     alloc((size_t)NBLK * 4);
    int*      start  = (int*)     alloc((size_t)(N_NODES + 1) * 4);
    int*      cursor = (int*)     alloc((size_t)N_NODES * 4);
    uint4*    rec    = (uint4*)   alloc((size_t)N_EDGES * 32);
    unsigned* y      = (unsigned*)alloc((size_t)N_NODES * 256 * 2);
    float*    hbuf   = (float*)   alloc((size_t)N_NODES * 64 * 4);

    (void)hipMemsetAsync(cnt, 0, (size_t)N_NODES * 4, stream);

    front_k<<<1024, 256, 0, stream>>>(nf, W0, y, dst, cnt);
    blk_scan_k<<<NBLK, 256, 0, stream>>>(cnt, esc, bsum);
    bsum_scan_k<<<1, 256, 0, stream>>>(bsum, boff, start);
    finalize_k<<<NBLK, 256, 0, stream>>>(esc, boff, start, cursor);
    scatter_k<<<(N_EDGES + 255) / 256, 256, 0, stream>>>(src, dst, ef, cursor, rec);
    agg_k<<<NGRP, 256, 0, stream>>>(rec, start, cnt, y, b0, hbuf);
    tr1_k<<<NUNITS, 256, 0, stream>>>(hbuf, W1, y);
    agg_fc_k<<<NGRP, 256, 0, stream>>>(rec + 1, start, cnt, y, b1, Wfc, bfc, out);
}